// Round 1
// baseline (202.604 us; speedup 1.0000x reference)
//
#include <hip/hip_runtime.h>

#define BB 16
#define CC 3
#define AA 9
#define HHH 128
#define WWW 128
#define MM 32
#define KK 8
#define HWSZ (HHH*WWW)          // 16384
#define NN (AA*HWSZ)            // 147456

#define KEYS_WORDS ((size_t)BB*NN)
#define STATS_STRIDE 32
#define ST_NPOS 0
#define ST_NNEG 1
#define ST_OBJP 2
#define ST_CLS  3
#define ST_LOC  4
#define ST_K    5
#define ST_R    6
#define ST_PREFIX 7
#define ST_SABOVE 8
#define ST_TOPK 9
#define STATS_WORDS (BB*STATS_STRIDE)
#define HIST_LVL_WORDS (BB*512)   // 256 counts + 256 f32 sums per image

// ---------------- K1: per-anchor losses, keys, level-0 histogram ----------------
__global__ __launch_bounds__(256) void k_main(
    const float* __restrict__ pred, const float* __restrict__ anchors,
    const float* __restrict__ gtb, const int* __restrict__ gtl,
    unsigned* __restrict__ keys, unsigned* __restrict__ stats,
    unsigned* __restrict__ hist0)
{
  __shared__ float s_bx1[MM], s_by1[MM], s_bx2[MM], s_by2[MM];
  __shared__ float s_area[MM], s_gx[MM], s_gy[MM], s_gw[MM], s_gh[MM];
  __shared__ int s_lab[MM];
  __shared__ unsigned s_hc[8][256];
  __shared__ float s_hs[8][256];
  __shared__ unsigned s_ri[2];
  __shared__ float s_rf[3];

  const int tid = threadIdx.x;
  const int b = blockIdx.x >> 6;
  const int hw = ((blockIdx.x & 63) << 8) + tid;

  for (int i = tid; i < 8*256; i += 256) { (&s_hc[0][0])[i] = 0u; (&s_hs[0][0])[i] = 0.f; }
  if (tid < 2) s_ri[tid] = 0u;
  if (tid < 3) s_rf[tid] = 0.f;
  if (tid < MM) {
    float x1 = gtb[((size_t)b*MM + tid)*4 + 0];
    float y1 = gtb[((size_t)b*MM + tid)*4 + 1];
    float x2 = gtb[((size_t)b*MM + tid)*4 + 2];
    float y2 = gtb[((size_t)b*MM + tid)*4 + 3];
    s_bx1[tid] = x1; s_by1[tid] = y1; s_bx2[tid] = x2; s_by2[tid] = y2;
    s_area[tid] = (x2 - x1) * (y2 - y1);
    s_gx[tid] = (x1 + x2) * 0.5f;
    s_gy[tid] = (y1 + y2) * 0.5f;
    s_gw[tid] = fmaxf(x2 - x1, 1e-6f);
    s_gh[tid] = fmaxf(y2 - y1, 1e-6f);
    s_lab[tid] = gtl[(size_t)b*MM + tid];
  }
  __syncthreads();

  const int rep = tid & 7;
  unsigned npos = 0, nneg = 0;
  float objp = 0.f, clss = 0.f, locs = 0.f;
  const float* pb = pred + (size_t)b * (AA*KK) * HWSZ + hw;

  for (int a = 0; a < AA; ++a) {
    float p[KK];
#pragma unroll
    for (int q = 0; q < KK; ++q) p[q] = pb[(size_t)(a*KK + q) * HWSZ];

    const int n = hw * AA + a;
    const float4 anc = ((const float4*)anchors)[n];
    const float area_a = (anc.z - anc.x) * (anc.w - anc.y);

    unsigned bi = 0;
    float binter, bunion;
    {
      float lx = fmaxf(anc.x, s_bx1[0]);
      float ly = fmaxf(anc.y, s_by1[0]);
      float rx = fminf(anc.z, s_bx2[0]);
      float ry = fminf(anc.w, s_by2[0]);
      float wx = fmaxf(rx - lx, 0.f);
      float wy = fmaxf(ry - ly, 0.f);
      binter = wx * wy;
      bunion = fmaxf(area_a + s_area[0] - binter, 1e-9f);
    }
    for (int j = 1; j < MM; ++j) {
      float lx = fmaxf(anc.x, s_bx1[j]);
      float ly = fmaxf(anc.y, s_by1[j]);
      float rx = fminf(anc.z, s_bx2[j]);
      float ry = fminf(anc.w, s_by2[j]);
      float wx = fmaxf(rx - lx, 0.f);
      float wy = fmaxf(ry - ly, 0.f);
      float inter = wx * wy;
      float uni = fmaxf(area_a + s_area[j] - inter, 1e-9f);
      // iou_j > iou_best  <=>  inter_j*union_best > inter_best*union_j  (all > 0)
      if (inter * bunion > binter * uni) { bi = (unsigned)j; binter = inter; bunion = uni; }
    }
    float best_iou = binter / bunion;
    bool pos = best_iou >= 0.5f;
    bool neg = best_iou < 0.3f;

    float x = p[4];
    float tt = pos ? 1.f : 0.f;
    float ol = fmaxf(x, 0.f) - x * tt + log1pf(expf(-fabsf(x)));

    unsigned key = 0u;
    if (neg) {
      key = __float_as_uint(ol);
      ++nneg;
      atomicAdd(&s_hc[rep][key >> 24], 1u);
      atomicAdd(&s_hs[rep][key >> 24], ol);
    }
    keys[((size_t)b * AA + a) * HWSZ + hw] = key;   // coalesced [b][a][hw]

    if (pos) {
      ++npos;
      objp += ol;
      int lab = s_lab[bi];
      int tgt = lab - 1; tgt = tgt < 0 ? 0 : (tgt > CC-1 ? CC-1 : tgt);
      float c0 = p[5], c1 = p[6], c2 = p[7];
      float m = fmaxf(fmaxf(c0, c1), c2);
      float lse = m + logf(expf(c0-m) + expf(c1-m) + expf(c2-m));
      float ct = (tgt == 0) ? c0 : ((tgt == 1) ? c1 : c2);
      clss += lse - ct;

      float axc = (anc.x + anc.z) * 0.5f;
      float ayc = (anc.y + anc.w) * 0.5f;
      float aw = fmaxf(anc.z - anc.x, 1e-6f);
      float ah = fmaxf(anc.w - anc.y, 1e-6f);
      float t0 = (s_gx[bi] - axc) / aw;
      float t1 = (s_gy[bi] - ayc) / ah;
      float t2 = logf(s_gw[bi] / aw);
      float t3 = logf(s_gh[bi] / ah);
      float l = 0.f, d, ad;
      d = p[0]-t0; ad = fabsf(d); l += (ad < 1.f) ? 0.5f*d*d : ad - 0.5f;
      d = p[1]-t1; ad = fabsf(d); l += (ad < 1.f) ? 0.5f*d*d : ad - 0.5f;
      d = p[2]-t2; ad = fabsf(d); l += (ad < 1.f) ? 0.5f*d*d : ad - 0.5f;
      d = p[3]-t3; ad = fabsf(d); l += (ad < 1.f) ? 0.5f*d*d : ad - 0.5f;
      locs += l;
    }
  }

  atomicAdd(&s_ri[0], npos);
  atomicAdd(&s_ri[1], nneg);
  atomicAdd(&s_rf[0], objp);
  atomicAdd(&s_rf[1], clss);
  atomicAdd(&s_rf[2], locs);
  __syncthreads();

  unsigned* st = stats + b * STATS_STRIDE;
  if (tid == 0) { atomicAdd(&st[ST_NPOS], s_ri[0]); atomicAdd(&st[ST_NNEG], s_ri[1]); }
  else if (tid == 1) atomicAdd((float*)(st + ST_OBJP), s_rf[0]);
  else if (tid == 2) atomicAdd((float*)(st + ST_CLS), s_rf[1]);
  else if (tid == 3) atomicAdd((float*)(st + ST_LOC), s_rf[2]);

  // merge replicated level-0 histogram to global (per image)
  unsigned c = 0; float s = 0.f;
#pragma unroll
  for (int r = 0; r < 8; ++r) { c += s_hc[r][tid]; s += s_hs[r][tid]; }
  if (c) {
    atomicAdd(&hist0[b*512 + tid], c);
    atomicAdd((float*)(hist0 + b*512 + 256 + tid), s);
  }
}

// ---------------- S0: compute k, select top 8 bits ----------------
__global__ void k_select0(unsigned* stats, unsigned* hist0)
{
  if (threadIdx.x != 0) return;
  int b = blockIdx.x;
  unsigned* st = stats + b * STATS_STRIDE;
  unsigned np = st[ST_NPOS], nn = st[ST_NNEG];
  unsigned k;
  if (np == 0u) k = (nn > 0u) ? ((nn/10u > 1u) ? nn/10u : 1u) : 0u;
  else          k = (3u*np < nn) ? 3u*np : nn;
  st[ST_K] = k;
  if (k == 0u) {
    st[ST_PREFIX] = 0xFFFFFFFFu; st[ST_R] = 0u;
    ((float*)st)[ST_SABOVE] = 0.f; ((float*)st)[ST_TOPK] = 0.f;
    return;
  }
  unsigned* hc = hist0 + b*512;
  float*    hs = (float*)(hc + 256);
  unsigned cum = 0; float ssum = 0.f; int chosen = 0;
  for (int bin = 255; bin >= 0; --bin) {
    unsigned cc = hc[bin];
    if (cum + cc >= k) { chosen = bin; break; }
    cum += cc; ssum += hs[bin];
  }
  st[ST_PREFIX] = (unsigned)chosen;
  st[ST_R] = k - cum;
  ((float*)st)[ST_SABOVE] = ssum;
}

// ---------------- H<SH>: histogram next 8 bits among prefix-matching keys ----------------
template<int SH>
__global__ __launch_bounds__(256) void k_hist(
    const unsigned* __restrict__ keys, const unsigned* __restrict__ stats,
    unsigned* __restrict__ hist)
{
  __shared__ unsigned s_hc[4][256];
  __shared__ float s_hs[4][256];
  const int tid = threadIdx.x;
  const int b = blockIdx.x >> 6;
  const unsigned* st = stats + b * STATS_STRIDE;
  const unsigned prefix = st[ST_PREFIX];
  const unsigned k = st[ST_K];

  for (int i = tid; i < 4*256; i += 256) { (&s_hc[0][0])[i] = 0u; (&s_hs[0][0])[i] = 0.f; }
  __syncthreads();

  if (k) {
    const size_t base = (size_t)blockIdx.x * 2304;
    const int rep = tid & 3;
#pragma unroll
    for (int j = 0; j < 9; ++j) {
      unsigned key = keys[base + (size_t)j*256 + tid];
      if ((key >> (SH + 8)) == prefix) {
        unsigned bin = (key >> SH) & 255u;
        atomicAdd(&s_hc[rep][bin], 1u);
        atomicAdd(&s_hs[rep][bin], __uint_as_float(key));
      }
    }
  }
  __syncthreads();

  unsigned c = 0; float s = 0.f;
#pragma unroll
  for (int r = 0; r < 4; ++r) { c += s_hc[r][tid]; s += s_hs[r][tid]; }
  if (c) {
    atomicAdd((unsigned*)&hist[b*512 + tid], c);
    atomicAdd((float*)(hist + b*512 + 256 + tid), s);
  }
}

// ---------------- S: extend prefix by 8 bits (final: compute topk sum) ----------------
__global__ void k_select(unsigned* stats, unsigned* hist, int final_level)
{
  if (threadIdx.x != 0) return;
  int b = blockIdx.x;
  unsigned* st = stats + b * STATS_STRIDE;
  unsigned k = st[ST_K];
  if (k == 0u) return;          // topk already 0
  unsigned r = st[ST_R];
  unsigned* hc = hist + b*512;
  float*    hs = (float*)(hc + 256);
  unsigned cum = 0; float ssum = 0.f; int chosen = 0;
  for (int bin = 255; bin >= 0; --bin) {
    unsigned cc = hc[bin];
    if (cum + cc >= r) { chosen = bin; break; }
    cum += cc; ssum += hs[bin];
  }
  unsigned prefix = (st[ST_PREFIX] << 8) | (unsigned)chosen;
  st[ST_PREFIX] = prefix;
  unsigned rem = r - cum;
  st[ST_R] = rem;
  float sab = ((float*)st)[ST_SABOVE] + ssum;
  ((float*)st)[ST_SABOVE] = sab;
  if (final_level) {
    // prefix is now the exact 32-bit threshold key t
    ((float*)st)[ST_TOPK] = sab + (float)rem * __uint_as_float(prefix);
  }
}

// ---------------- F: combine images, write 4 losses ----------------
__global__ void k_final(const unsigned* __restrict__ stats, float* __restrict__ out)
{
  if (threadIdx.x != 0 || blockIdx.x != 0) return;
  unsigned tp = 0, ts = 0;
  float obj = 0.f, cls = 0.f, loc = 0.f;
  for (int b = 0; b < BB; ++b) {
    const unsigned* st = stats + b * STATS_STRIDE;
    unsigned np = st[ST_NPOS], k = st[ST_K];
    tp += np; ts += np + k;
    obj += ((const float*)st)[ST_OBJP] + ((const float*)st)[ST_TOPK];
    cls += ((const float*)st)[ST_CLS];
    loc += ((const float*)st)[ST_LOC];
  }
  float dp  = (float)(tp > 1u ? tp : 1u);
  float dob = (float)(ts > 1u ? ts : 1u);
  float lo = obj / dob, lc = cls / dp, ll = loc / dp;
  out[0] = lo;
  out[1] = lc;
  out[2] = ll;
  out[3] = 2.f*ll + lc + lo;
}

extern "C" void kernel_launch(void* const* d_in, const int* in_sizes, int n_in,
                              void* d_out, int out_size, void* d_ws, size_t ws_size,
                              hipStream_t stream)
{
  const float* pred    = (const float*)d_in[0];
  const float* anchors = (const float*)d_in[1];
  const float* gtb     = (const float*)d_in[2];
  const int*   gtl     = (const int*)d_in[3];
  float* out = (float*)d_out;

  unsigned* ws    = (unsigned*)d_ws;
  unsigned* keys  = ws;
  unsigned* stats = ws + KEYS_WORDS;
  unsigned* h0    = stats + STATS_WORDS;
  unsigned* h1    = h0 + HIST_LVL_WORDS;
  unsigned* h2    = h1 + HIST_LVL_WORDS;
  unsigned* h3    = h2 + HIST_LVL_WORDS;

  hipMemsetAsync(stats, 0, (size_t)(STATS_WORDS + 4*HIST_LVL_WORDS)*4, stream);

  k_main<<<BB*64, 256, 0, stream>>>(pred, anchors, gtb, gtl, keys, stats, h0);
  k_select0<<<BB, 64, 0, stream>>>(stats, h0);
  k_hist<16><<<BB*64, 256, 0, stream>>>(keys, stats, h1);
  k_select<<<BB, 64, 0, stream>>>(stats, h1, 0);
  k_hist<8><<<BB*64, 256, 0, stream>>>(keys, stats, h2);
  k_select<<<BB, 64, 0, stream>>>(stats, h2, 0);
  k_hist<0><<<BB*64, 256, 0, stream>>>(keys, stats, h3);
  k_select<<<BB, 64, 0, stream>>>(stats, h3, 1);
  k_final<<<1, 64, 0, stream>>>(stats, out);
}